// Round 6
// baseline (226.812 us; speedup 1.0000x reference)
//
#include <hip/hip_runtime.h>
#include <hip/hip_cooperative_groups.h>
#include <stdint.h>

namespace cg = cooperative_groups;

// Problem constants (B, N, H, L) = (4096, 512, 1024, 8)
static constexpr int B_DIM = 4096;
static constexpr int N_DIM = 512;
static constexpr int H_DIM = 1024;
static constexpr int L_DIM = 8;
static constexpr int HL    = H_DIM * L_DIM;   // 8192

typedef __attribute__((ext_vector_type(8))) short short8;     // 8 bf16 (4 VGPRs)
typedef __attribute__((ext_vector_type(8))) unsigned short u16x8;
typedef __attribute__((ext_vector_type(4))) float f32x4;

// round-to-nearest-even fp32 -> bf16 (bit pattern)
__device__ __forceinline__ uint16_t f2bf(float f) {
  uint32_t u = __float_as_uint(f);
  u += 0x7fffu + ((u >> 16) & 1u);
  return (uint16_t)(u >> 16);
}

__device__ __forceinline__ void stage16(const uint16_t* g, uint16_t* l) {
  __builtin_amdgcn_global_load_lds(
      (const __attribute__((address_space(1))) void*)g,
      (__attribute__((address_space(3))) void*)l, 16, 0, 0);
}

// elementwise square of 8 packed bf16 (truncating round; bias << tolerance).
// 7 VALU ops per dword — avoids staging an x^2 half-tile entirely.
__device__ __forceinline__ short8 sq8(short8 a) {
  union { short8 s; uint32_t u[4]; } in, out;
  in.s = a;
#pragma unroll
  for (int d = 0; d < 4; ++d) {
    uint32_t lo = in.u[d] << 16;
    uint32_t hi = in.u[d] & 0xffff0000u;
    float fl = __uint_as_float(lo), fh = __uint_as_float(hi);
    fl *= fl; fh *= fh;
    out.u[d] = (__float_as_uint(fh) & 0xffff0000u) | (__float_as_uint(fl) >> 16);
  }
  return out.s;
}

// ---------- phase 1: prep (grid-stride) ----------
// betab = bf16(beta) (HL,N); xb = bf16(x) (B,N);
// combW[h,0:512]=bf16(W), [512:1024]=bf16(-0.5*sum_l beta^2)  (H, 1024)
__device__ __forceinline__ void prep_phase(int gtid, int gsize,
    const float* __restrict__ x, const float* __restrict__ beta,
    const float* __restrict__ W, uint16_t* __restrict__ xb,
    uint16_t* __restrict__ betab, uint16_t* __restrict__ combW) {
  for (int t = gtid; t < HL * N_DIM / 8; t += gsize) {
    const f32x4* src = (const f32x4*)(beta + (size_t)t * 8);
    f32x4 a = src[0], b = src[1];
    u16x8 o;
#pragma unroll
    for (int i = 0; i < 4; ++i) { o[i] = f2bf(a[i]); o[4 + i] = f2bf(b[i]); }
    *(u16x8*)(betab + (size_t)t * 8) = o;
  }
  for (int t = gtid; t < B_DIM * N_DIM / 8; t += gsize) {
    const f32x4* src = (const f32x4*)(x + (size_t)t * 8);
    f32x4 a = src[0], b = src[1];
    u16x8 o;
#pragma unroll
    for (int i = 0; i < 4; ++i) { o[i] = f2bf(a[i]); o[4 + i] = f2bf(b[i]); }
    *(u16x8*)(xb + (size_t)t * 8) = o;
  }
  for (int t = gtid; t < H_DIM * N_DIM / 8; t += gsize) {
    int h = t >> 6, n8 = (t & 63) * 8;
    const f32x4* wsrc = (const f32x4*)(W + (size_t)h * N_DIM + n8);
    f32x4 wa = wsrc[0], wb = wsrc[1];
    u16x8 lo;
#pragma unroll
    for (int i = 0; i < 4; ++i) { lo[i] = f2bf(wa[i]); lo[4 + i] = f2bf(wb[i]); }
    *(u16x8*)(combW + (size_t)h * 1024 + n8) = lo;
    float s[8] = {};
#pragma unroll
    for (int l = 0; l < L_DIM; ++l) {
      const f32x4* bsrc = (const f32x4*)(beta + ((size_t)h * L_DIM + l) * N_DIM + n8);
      f32x4 a = bsrc[0], b = bsrc[1];
#pragma unroll
      for (int i = 0; i < 4; ++i) { s[i] += a[i] * a[i]; s[4 + i] += b[i] * b[i]; }
    }
    u16x8 hi;
#pragma unroll
    for (int i = 0; i < 8; ++i) hi[i] = f2bf(-0.5f * s[i]);
    *(u16x8*)(combW + (size_t)h * 1024 + 512 + n8) = hi;
  }
}

// ---------- phase 2: one 128x128 FM tile + its 128x16 linear tile ----------
// FM: out(b, h) += 0.5*sum_l s^2 over betab cols; linear folded into same
// kt-loop: wn0 waves MFMA(x, Wlo), wn1 waves MFMA(x^2(in-reg), Whi).
// LDS swizzle: row m = 8 chunks of 16B, slot = c ^ (m&7); Ws 16x16 chunks,
// slot = c ^ m. Epilogue reduction tile `red` stride 20 (2-way banks, 16B ok).
__device__ __forceinline__ void gemm_tile(int bx, int by, int tid,
    const uint16_t* __restrict__ xb, const uint16_t* __restrict__ betab,
    const uint16_t* __restrict__ combW, const float* __restrict__ bias,
    float* __restrict__ out, uint16_t* As, uint16_t* Bs, uint16_t* Ws) {
  const int lane = tid & 63;
  const int wave = tid >> 6;
  const int wm = wave >> 1, wn = wave & 1;
  const int fr = lane & 15, quad = lane >> 4;
  const int row0 = by * 128, col0 = bx * 128, hcol0 = bx * 16;

  f32x4 acc[4][4] = {};
  f32x4 lacc[4] = {};

  for (int kt = 0; kt < N_DIM; kt += 64) {
#pragma unroll
    for (int u = 0; u < 4; ++u) {   // A: x tile, 1024 chunks
      int s = tid + u * 256, m = s >> 3, cp = s & 7, c = cp ^ (m & 7);
      stage16(xb + (size_t)(row0 + m) * N_DIM + kt + c * 8, As + s * 8);
    }
#pragma unroll
    for (int u = 0; u < 4; ++u) {   // B: betab tile, 1024 chunks
      int s = tid + u * 256, m = s >> 3, cp = s & 7, c = cp ^ (m & 7);
      stage16(betab + (size_t)(col0 + m) * N_DIM + kt + c * 8, Bs + s * 8);
    }
    {                               // W: 16 rows x (lo64|hi64), 256 chunks
      int m = tid >> 4, cp = tid & 15, c = cp ^ m;
      int col = (c >> 3) * N_DIM + kt + (c & 7) * 8;
      stage16(combW + (size_t)(hcol0 + m) * 1024 + col, Ws + tid * 8);
    }
    __syncthreads();

#pragma unroll
    for (int kk2 = 0; kk2 < 2; ++kk2) {
      const int cbase = kk2 * 4 + quad;
      short8 af[4], bf[4], wf;
#pragma unroll
      for (int i = 0; i < 4; ++i) {
        int m = wm * 64 + i * 16 + fr;
        af[i] = *(const short8*)(As + (m * 8 + (cbase ^ (m & 7))) * 8);
      }
#pragma unroll
      for (int j = 0; j < 4; ++j) {
        int m = wn * 64 + j * 16 + fr;
        bf[j] = *(const short8*)(Bs + (m * 8 + (cbase ^ (m & 7))) * 8);
      }
      wf = *(const short8*)(Ws + (fr * 16 + ((wn * 8 + cbase) ^ fr)) * 8);
#pragma unroll
      for (int i = 0; i < 4; ++i)
#pragma unroll
        for (int j = 0; j < 4; ++j)
          acc[i][j] = __builtin_amdgcn_mfma_f32_16x16x32_bf16(af[i], bf[j], acc[i][j], 0, 0, 0);
      if (wn == 0) {
#pragma unroll
        for (int i = 0; i < 4; ++i)
          lacc[i] = __builtin_amdgcn_mfma_f32_16x16x32_bf16(af[i], wf, lacc[i], 0, 0, 0);
      } else {
#pragma unroll
        for (int i = 0; i < 4; ++i)
          lacc[i] = __builtin_amdgcn_mfma_f32_16x16x32_bf16(sq8(af[i]), wf, lacc[i], 0, 0, 0);
      }
    }
    __syncthreads();
  }

  // ---- epilogue: lin partials + FM butterfly meet in LDS, coalesced store ----
  float* red = (float*)As;   // 128 x 20 f32 = 10 KB (As free after last sync)
  if (wn == 0) {
#pragma unroll
    for (int i = 0; i < 4; ++i)
#pragma unroll
      for (int r = 0; r < 4; ++r)
        red[(wm * 64 + i * 16 + quad * 4 + r) * 20 + fr] = lacc[i][r];
  }
  __syncthreads();
  if (wn == 1) {
#pragma unroll
    for (int i = 0; i < 4; ++i)
#pragma unroll
      for (int r = 0; r < 4; ++r)
        red[(wm * 64 + i * 16 + quad * 4 + r) * 20 + fr] += lacc[i][r];
  }
  __syncthreads();
  // FM: C/D layout col=lane&15 (hl-local), row=quad*4+reg; butterfly over l
#pragma unroll
  for (int i = 0; i < 4; ++i)
#pragma unroll
    for (int j = 0; j < 4; ++j) {
      const int hin = wn * 8 + j * 2 + (fr >> 3);
#pragma unroll
      for (int r = 0; r < 4; ++r) {
        float v = acc[i][j][r];
        v = v * v;
        v += __shfl_xor(v, 1);
        v += __shfl_xor(v, 2);
        v += __shfl_xor(v, 4);
        if ((lane & 7) == 0)
          red[(wm * 64 + i * 16 + quad * 4 + r) * 20 + hin] += 0.5f * v;
      }
    }
  __syncthreads();
#pragma unroll
  for (int u = 0; u < 2; ++u) {
    int s = tid + u * 256;           // 0..511
    int r = s >> 2, hc4 = (s & 3) * 4;
    f32x4 b4 = *(const f32x4*)(bias + hcol0 + hc4);
    f32x4 v  = *(const f32x4*)(red + r * 20 + hc4);
    f32x4 o;
#pragma unroll
    for (int c = 0; c < 4; ++c) o[c] = v[c] + b4[c];
    *(f32x4*)(out + (size_t)(row0 + r) * H_DIM + hcol0 + hc4) = o;
  }
  __syncthreads();   // red (As) is restaged by the next tile
}

// ---------- cooperative all-in-one: prep -> grid.sync -> 4 tiles/block ----------
__global__ __launch_bounds__(256, 2) void fused_all(
    const float* __restrict__ x, const float* __restrict__ beta,
    const float* __restrict__ W, const float* __restrict__ bias,
    uint16_t* __restrict__ xb, uint16_t* __restrict__ betab,
    uint16_t* __restrict__ combW, float* __restrict__ out) {
  __shared__ __align__(16) uint16_t As[128 * 64];  // 16 KB
  __shared__ __align__(16) uint16_t Bs[128 * 64];  // 16 KB
  __shared__ __align__(16) uint16_t Ws[16 * 128];  //  4 KB
  const int tid = threadIdx.x, bid = blockIdx.x;
  prep_phase(bid * 256 + tid, 512 * 256, x, beta, W, xb, betab, combW);
  cg::this_grid().sync();
#pragma unroll 1
  for (int tt = 0; tt < 4; ++tt) {
    int T = tt * 512 + bid;          // 512 blocks x 4 tiles = 2048, uniform
    gemm_tile(T & 63, T >> 6, tid, xb, betab, combW, bias, out, As, Bs, Ws);
  }
}

// ---------- non-cooperative fallback (same device code, 2 launches) ----------
__global__ void prep_only(const float* x, const float* beta, const float* W,
                          uint16_t* xb, uint16_t* betab, uint16_t* combW) {
  prep_phase(blockIdx.x * 256 + threadIdx.x, gridDim.x * 256, x, beta, W, xb, betab, combW);
}
__global__ __launch_bounds__(256) void gemm_only(
    const uint16_t* xb, const uint16_t* betab, const uint16_t* combW,
    const float* bias, float* out) {
  __shared__ __align__(16) uint16_t As[128 * 64];
  __shared__ __align__(16) uint16_t Bs[128 * 64];
  __shared__ __align__(16) uint16_t Ws[16 * 128];
  gemm_tile(blockIdx.x, blockIdx.y, threadIdx.x, xb, betab, combW, bias, out, As, Bs, Ws);
}

extern "C" void kernel_launch(void* const* d_in, const int* in_sizes, int n_in,
                              void* d_out, int out_size, void* d_ws, size_t ws_size,
                              hipStream_t stream) {
  const float* x    = (const float*)d_in[0];  // (4096, 512)
  const float* beta = (const float*)d_in[1];  // (1024, 8, 512)
  const float* W    = (const float*)d_in[2];  // (1024, 512)
  const float* bias = (const float*)d_in[3];  // (1024,)
  float* out = (float*)d_out;                 // (4096, 1024)

  uint16_t* xb    = (uint16_t*)d_ws;                        // 4096*512 bf16 = 4 MB
  uint16_t* betab = xb + (size_t)B_DIM * N_DIM;             // 8192*512 bf16 = 8 MB
  uint16_t* combW = betab + (size_t)HL * N_DIM;             // 1024*1024 bf16 = 2 MB

  void* args[] = {(void*)&x, (void*)&beta, (void*)&W, (void*)&bias,
                  (void*)&xb, (void*)&betab, (void*)&combW, (void*)&out};
  hipError_t e = hipLaunchCooperativeKernel((const void*)fused_all,
                                            dim3(512), dim3(256), args, 0, stream);
  if (e != hipSuccess) {
    // fallback: same device code, split at the sync point
    prep_only<<<2048, 256, 0, stream>>>(x, beta, W, xb, betab, combW);
    gemm_only<<<dim3(64, 32), 256, 0, stream>>>(xb, betab, combW, bias, out);
  }
}

// Round 7
// 210.418 us; speedup vs baseline: 1.0779x; 1.0779x over previous
//
#include <hip/hip_runtime.h>
#include <stdint.h>

// Problem constants (B, N, H, L) = (4096, 512, 1024, 8)
static constexpr int B_DIM = 4096;
static constexpr int N_DIM = 512;
static constexpr int H_DIM = 1024;
static constexpr int L_DIM = 8;
static constexpr int HL    = H_DIM * L_DIM;   // 8192

typedef __attribute__((ext_vector_type(8))) short short8;     // 8 bf16 (4 VGPRs)
typedef __attribute__((ext_vector_type(8))) unsigned short u16x8;
typedef __attribute__((ext_vector_type(4))) float f32x4;

// round-to-nearest-even fp32 -> bf16 (bit pattern)
__device__ __forceinline__ uint16_t f2bf(float f) {
  uint32_t u = __float_as_uint(f);
  u += 0x7fffu + ((u >> 16) & 1u);
  return (uint16_t)(u >> 16);
}

__device__ __forceinline__ void stage16(const uint16_t* g, uint16_t* l) {
  __builtin_amdgcn_global_load_lds(
      (const __attribute__((address_space(1))) void*)g,
      (__attribute__((address_space(3))) void*)l, 16, 0, 0);
}

// elementwise square of 8 packed bf16 (truncating round; bias << tolerance)
__device__ __forceinline__ short8 sq8(short8 a) {
  union { short8 s; uint32_t u[4]; } in, out;
  in.s = a;
#pragma unroll
  for (int d = 0; d < 4; ++d) {
    uint32_t lo = in.u[d] << 16;
    uint32_t hi = in.u[d] & 0xffff0000u;
    float fl = __uint_as_float(lo), fh = __uint_as_float(hi);
    fl *= fl; fh *= fh;
    out.u[d] = (__float_as_uint(fh) & 0xffff0000u) | (__float_as_uint(fl) >> 16);
  }
  return out.s;
}

// ---------- prep kernel (8 elems/thread, 16B stores) ----------
// region 0: betab = bf16(beta)  (HL,N)
// region 1: xb = bf16(x)        (B,N)
// region 2: combW[h,0:512]=bf16(W), [512:1024]=bf16(-0.5*sum_l beta^2)  (H,1024)
static constexpr int PREP_T0 = HL * N_DIM / 8;       // 524288
static constexpr int PREP_T1 = B_DIM * N_DIM / 8;    // 262144
static constexpr int PREP_T2 = H_DIM * N_DIM / 8;    // 65536

__global__ void prep_kernel(const float* __restrict__ x, const float* __restrict__ beta,
                            const float* __restrict__ W,
                            uint16_t* __restrict__ xb, uint16_t* __restrict__ betab,
                            uint16_t* __restrict__ combW) {
  int t = blockIdx.x * 256 + threadIdx.x;
  if (t < PREP_T0) {                           // beta cast
    const f32x4* src = (const f32x4*)(beta + (size_t)t * 8);
    f32x4 a = src[0], b = src[1];
    u16x8 o;
#pragma unroll
    for (int i = 0; i < 4; ++i) { o[i] = f2bf(a[i]); o[4 + i] = f2bf(b[i]); }
    *(u16x8*)(betab + (size_t)t * 8) = o;
    return;
  }
  t -= PREP_T0;
  if (t < PREP_T1) {                           // x cast
    const f32x4* src = (const f32x4*)(x + (size_t)t * 8);
    f32x4 a = src[0], b = src[1];
    u16x8 o;
#pragma unroll
    for (int i = 0; i < 4; ++i) { o[i] = f2bf(a[i]); o[4 + i] = f2bf(b[i]); }
    *(u16x8*)(xb + (size_t)t * 8) = o;
    return;
  }
  t -= PREP_T1;                                // W | -0.5*sum_l beta^2
  int h = t >> 6, n8 = (t & 63) * 8;
  const f32x4* wsrc = (const f32x4*)(W + (size_t)h * N_DIM + n8);
  f32x4 wa = wsrc[0], wb = wsrc[1];
  u16x8 lo;
#pragma unroll
  for (int i = 0; i < 4; ++i) { lo[i] = f2bf(wa[i]); lo[4 + i] = f2bf(wb[i]); }
  *(u16x8*)(combW + (size_t)h * 1024 + n8) = lo;
  float s[8] = {};
#pragma unroll
  for (int l = 0; l < L_DIM; ++l) {
    const f32x4* bsrc = (const f32x4*)(beta + ((size_t)h * L_DIM + l) * N_DIM + n8);
    f32x4 a = bsrc[0], b = bsrc[1];
#pragma unroll
    for (int i = 0; i < 4; ++i) { s[i] += a[i] * a[i]; s[4 + i] += b[i] * b[i]; }
  }
  u16x8 hi;
#pragma unroll
  for (int i = 0; i < 8; ++i) hi[i] = f2bf(-0.5f * s[i]);
  *(u16x8*)(combW + (size_t)h * 1024 + 512 + n8) = hi;
}

// ---------- fused GEMM: one 128x128 FM tile + its 128x16 linear tile ----------
// FM: out(b,h) = 0.5*sum_l s^2; linear folded into the same kt loop.
// Linear split: wave (wm,wn) owns lin rows wm*64+wn*32+{0,16} (its m-frags
// wn*2, wn*2+1) and accumulates BOTH halves (x@Wlo + x^2@Whi, x^2 in-register
// via sq8) into lacc[2] -> 72 AGPR total; with launch_bounds(256,3) the block
// fits 3/CU (vs 2 at R5/R6's 172 regs).
// LDS swizzle: row m = 8 chunks of 16B, slot = c ^ (m&7); Ws 16 rows x 16
// chunks (lo 0-7 | hi 8-15), slot = c ^ m. Quad reads land 2-way = free.
__global__ __launch_bounds__(256, 3) void gemm_kernel(
    const uint16_t* __restrict__ xb,      // (B, N)
    const uint16_t* __restrict__ betab,   // (HL, N)
    const uint16_t* __restrict__ combW,   // (H, 1024)
    const float* __restrict__ bias,       // (H,)
    float* __restrict__ out)              // (B, H)
{
  __shared__ __align__(16) uint16_t As[128 * 64];  // 16 KB
  __shared__ __align__(16) uint16_t Bs[128 * 64];  // 16 KB
  __shared__ __align__(16) uint16_t Ws[16 * 128];  //  4 KB

  const int tid  = threadIdx.x;
  const int lane = tid & 63;
  const int wave = tid >> 6;
  const int wm = wave >> 1, wn = wave & 1;
  const int fr = lane & 15, quad = lane >> 4;
  const int row0 = blockIdx.y * 128, col0 = blockIdx.x * 128, hcol0 = blockIdx.x * 16;

  f32x4 acc[4][4] = {};
  f32x4 lacc[2] = {};

  for (int kt = 0; kt < N_DIM; kt += 64) {
#pragma unroll
    for (int u = 0; u < 4; ++u) {   // A: x tile, 1024 chunks
      int s = tid + u * 256, m = s >> 3, cp = s & 7, c = cp ^ (m & 7);
      stage16(xb + (size_t)(row0 + m) * N_DIM + kt + c * 8, As + s * 8);
    }
#pragma unroll
    for (int u = 0; u < 4; ++u) {   // B: betab tile, 1024 chunks
      int s = tid + u * 256, m = s >> 3, cp = s & 7, c = cp ^ (m & 7);
      stage16(betab + (size_t)(col0 + m) * N_DIM + kt + c * 8, Bs + s * 8);
    }
    {                               // W: 16 rows x (lo64|hi64), 256 chunks
      int m = tid >> 4, cp = tid & 15, c = cp ^ m;
      int col = (c >> 3) * N_DIM + kt + (c & 7) * 8;
      stage16(combW + (size_t)(hcol0 + m) * 1024 + col, Ws + tid * 8);
    }
    __syncthreads();

#pragma unroll
    for (int kk2 = 0; kk2 < 2; ++kk2) {
      const int cbase = kk2 * 4 + quad;
      short8 af[4], bf[4];
#pragma unroll
      for (int i = 0; i < 4; ++i) {
        int m = wm * 64 + i * 16 + fr;
        af[i] = *(const short8*)(As + (m * 8 + (cbase ^ (m & 7))) * 8);
      }
#pragma unroll
      for (int j = 0; j < 4; ++j) {
        int m = wn * 64 + j * 16 + fr;
        bf[j] = *(const short8*)(Bs + (m * 8 + (cbase ^ (m & 7))) * 8);
      }
      short8 wlo = *(const short8*)(Ws + (fr * 16 + (cbase ^ fr)) * 8);
      short8 whi = *(const short8*)(Ws + (fr * 16 + ((8 + cbase) ^ fr)) * 8);
#pragma unroll
      for (int i = 0; i < 4; ++i)
#pragma unroll
        for (int j = 0; j < 4; ++j)
          acc[i][j] = __builtin_amdgcn_mfma_f32_16x16x32_bf16(af[i], bf[j], acc[i][j], 0, 0, 0);
      // linear: this wave's 2 m-frags, both halves into the same accumulator
      short8 a0, a1;
      if (wn == 0) { a0 = af[0]; a1 = af[1]; } else { a0 = af[2]; a1 = af[3]; }
      lacc[0] = __builtin_amdgcn_mfma_f32_16x16x32_bf16(a0, wlo, lacc[0], 0, 0, 0);
      lacc[1] = __builtin_amdgcn_mfma_f32_16x16x32_bf16(a1, wlo, lacc[1], 0, 0, 0);
      lacc[0] = __builtin_amdgcn_mfma_f32_16x16x32_bf16(sq8(a0), whi, lacc[0], 0, 0, 0);
      lacc[1] = __builtin_amdgcn_mfma_f32_16x16x32_bf16(sq8(a1), whi, lacc[1], 0, 0, 0);
    }
    __syncthreads();
  }

  // ---- epilogue: lin rows (disjoint per wave) + FM butterfly meet in LDS ----
  float* red = (float*)As;   // 128 x 20 f32 = 10 KB (As free after last sync)
#pragma unroll
  for (int t = 0; t < 2; ++t)
#pragma unroll
    for (int r = 0; r < 4; ++r)
      red[(wm * 64 + wn * 32 + t * 16 + quad * 4 + r) * 20 + fr] = lacc[t][r];
  __syncthreads();
  // FM: C/D layout col=lane&15 (hl-local), row=quad*4+reg; butterfly over l
#pragma unroll
  for (int i = 0; i < 4; ++i)
#pragma unroll
    for (int j = 0; j < 4; ++j) {
      const int hin = wn * 8 + j * 2 + (fr >> 3);
#pragma unroll
      for (int r = 0; r < 4; ++r) {
        float v = acc[i][j][r];
        v = v * v;
        v += __shfl_xor(v, 1);
        v += __shfl_xor(v, 2);
        v += __shfl_xor(v, 4);
        if ((lane & 7) == 0)
          red[(wm * 64 + i * 16 + quad * 4 + r) * 20 + hin] += 0.5f * v;
      }
    }
  __syncthreads();
#pragma unroll
  for (int u = 0; u < 2; ++u) {
    int s = tid + u * 256;           // 0..511
    int r = s >> 2, hc4 = (s & 3) * 4;
    f32x4 b4 = *(const f32x4*)(bias + hcol0 + hc4);
    f32x4 v  = *(const f32x4*)(red + r * 20 + hc4);
    f32x4 o;
#pragma unroll
    for (int c = 0; c < 4; ++c) o[c] = v[c] + b4[c];
    *(f32x4*)(out + (size_t)(row0 + r) * H_DIM + hcol0 + hc4) = o;
  }
}

extern "C" void kernel_launch(void* const* d_in, const int* in_sizes, int n_in,
                              void* d_out, int out_size, void* d_ws, size_t ws_size,
                              hipStream_t stream) {
  const float* x    = (const float*)d_in[0];  // (4096, 512)
  const float* beta = (const float*)d_in[1];  // (1024, 8, 512)
  const float* W    = (const float*)d_in[2];  // (1024, 512)
  const float* bias = (const float*)d_in[3];  // (1024,)
  float* out = (float*)d_out;                 // (4096, 1024)

  uint16_t* xb    = (uint16_t*)d_ws;                        // 4096*512 bf16 = 4 MB
  uint16_t* betab = xb + (size_t)B_DIM * N_DIM;             // 8192*512 bf16 = 8 MB
  uint16_t* combW = betab + (size_t)HL * N_DIM;             // 1024*1024 bf16 = 2 MB

  const int prep_threads = PREP_T0 + PREP_T1 + PREP_T2;     // 851968
  prep_kernel<<<prep_threads / 256, 256, 0, stream>>>(x, beta, W, xb, betab, combW);

  // 2048 uniform blocks: 128 b-rows x 128 hl-cols (= 16 h) each, lin fused
  gemm_kernel<<<dim3(HL / 128, B_DIM / 128), 256, 0, stream>>>(
      xb, betab, combW, bias, out);
}

// Round 9
// 200.788 us; speedup vs baseline: 1.1296x; 1.0480x over previous
//
#include <hip/hip_runtime.h>
#include <stdint.h>

// Problem constants (B, N, H, L) = (4096, 512, 1024, 8)
static constexpr int B_DIM = 4096;
static constexpr int N_DIM = 512;
static constexpr int H_DIM = 1024;
static constexpr int L_DIM = 8;
static constexpr int HL    = H_DIM * L_DIM;   // 8192

typedef __attribute__((ext_vector_type(8))) short short8;     // 8 bf16 (4 VGPRs)
typedef __attribute__((ext_vector_type(8))) unsigned short u16x8;
typedef __attribute__((ext_vector_type(4))) float f32x4;

// round-to-nearest-even fp32 -> bf16 (bit pattern)
__device__ __forceinline__ uint16_t f2bf(float f) {
  uint32_t u = __float_as_uint(f);
  u += 0x7fffu + ((u >> 16) & 1u);
  return (uint16_t)(u >> 16);
}

__device__ __forceinline__ void stage16(const uint16_t* g, uint16_t* l) {
  __builtin_amdgcn_global_load_lds(
      (const __attribute__((address_space(1))) void*)g,
      (__attribute__((address_space(3))) void*)l, 16, 0, 0);
}

// elementwise square of 8 packed bf16 (truncating round; bias << tolerance)
__device__ __forceinline__ short8 sq8(short8 a) {
  union { short8 s; uint32_t u[4]; } in, out;
  in.s = a;
#pragma unroll
  for (int d = 0; d < 4; ++d) {
    uint32_t lo = in.u[d] << 16;
    uint32_t hi = in.u[d] & 0xffff0000u;
    float fl = __uint_as_float(lo), fh = __uint_as_float(hi);
    fl *= fl; fh *= fh;
    out.u[d] = (__float_as_uint(fh) & 0xffff0000u) | (__float_as_uint(fl) >> 16);
  }
  return out.s;
}

// ---------- prep kernel (8 elems/thread, 16B stores) ----------
// Region ORDER matters: combW first (scattered beta reads, heaviest per
// thread) so its 256 blocks start at t=0 instead of forming a 1-block/CU
// tail behind the cast blocks (R7 lesson).
static constexpr int PREP_T2 = H_DIM * N_DIM / 8;    // 65536  (combW)
static constexpr int PREP_T0 = HL * N_DIM / 8;       // 524288 (beta cast)
static constexpr int PREP_T1 = B_DIM * N_DIM / 8;    // 262144 (x cast)

__global__ void prep_kernel(const float* __restrict__ x, const float* __restrict__ beta,
                            const float* __restrict__ W,
                            uint16_t* __restrict__ xb, uint16_t* __restrict__ betab,
                            uint16_t* __restrict__ combW) {
  int t = blockIdx.x * 256 + threadIdx.x;
  if (t < PREP_T2) {                           // combW: W | -0.5*sum_l beta^2
    int h = t >> 6, n8 = (t & 63) * 8;
    const f32x4* wsrc = (const f32x4*)(W + (size_t)h * N_DIM + n8);
    f32x4 wa = wsrc[0], wb = wsrc[1];
    u16x8 lo;
#pragma unroll
    for (int i = 0; i < 4; ++i) { lo[i] = f2bf(wa[i]); lo[4 + i] = f2bf(wb[i]); }
    *(u16x8*)(combW + (size_t)h * 1024 + n8) = lo;
    float s[8] = {};
#pragma unroll
    for (int l = 0; l < L_DIM; ++l) {
      const f32x4* bsrc = (const f32x4*)(beta + ((size_t)h * L_DIM + l) * N_DIM + n8);
      f32x4 a = bsrc[0], b = bsrc[1];
#pragma unroll
      for (int i = 0; i < 4; ++i) { s[i] += a[i] * a[i]; s[4 + i] += b[i] * b[i]; }
    }
    u16x8 hi;
#pragma unroll
    for (int i = 0; i < 8; ++i) hi[i] = f2bf(-0.5f * s[i]);
    *(u16x8*)(combW + (size_t)h * 1024 + 512 + n8) = hi;
    return;
  }
  t -= PREP_T2;
  if (t < PREP_T0) {                           // beta cast
    const f32x4* src = (const f32x4*)(beta + (size_t)t * 8);
    f32x4 a = src[0], b = src[1];
    u16x8 o;
#pragma unroll
    for (int i = 0; i < 4; ++i) { o[i] = f2bf(a[i]); o[4 + i] = f2bf(b[i]); }
    *(u16x8*)(betab + (size_t)t * 8) = o;
    return;
  }
  t -= PREP_T0;                                // x cast
  const f32x4* src = (const f32x4*)(x + (size_t)t * 8);
  f32x4 a = src[0], b = src[1];
  u16x8 o;
#pragma unroll
  for (int i = 0; i < 4; ++i) { o[i] = f2bf(a[i]); o[4 + i] = f2bf(b[i]); }
  *(u16x8*)(xb + (size_t)t * 8) = o;
}

// ---------- fused GEMM: 64x128 FM tile + its 64x16 linear tile ----------
// Grid (64 bx, 64 by): block = 64 b-rows x 128 hl-cols (= 16 h, no lin waste).
// Per-wave: FM acc 2x4 frags (32 AGPR), lin lacc[1] (4 AGPR): wave (wm,wn)
// owns lin rows wm*32+wn*16, A-frag af[wn], x^2 via in-register sq8.
// Est ~115 regs -> honest 3 blocks/CU at launch_bounds(256,3), NO spill
// (R7 lesson: forcing min-waves past the need+headroom spills ~87 MB).
// LDS swizzle: row m = 8 chunks of 16B, slot c ^ (m&7); Ws 16 rows x 16
// chunks (lo 0-7 | hi 8-15), slot c ^ m. Quad reads 2-way = free (m136).
__global__ __launch_bounds__(256, 3) void gemm_kernel(
    const uint16_t* __restrict__ xb,      // (B, N)
    const uint16_t* __restrict__ betab,   // (HL, N)
    const uint16_t* __restrict__ combW,   // (H, 1024)
    const float* __restrict__ bias,       // (H,)
    float* __restrict__ out)              // (B, H)
{
  __shared__ __align__(16) uint16_t As[64 * 64];    //  8 KB
  __shared__ __align__(16) uint16_t Bs[128 * 64];   // 16 KB
  __shared__ __align__(16) uint16_t Ws[16 * 128];   //  4 KB

  const int tid  = threadIdx.x;
  const int lane = tid & 63;
  const int wave = tid >> 6;
  const int wm = wave >> 1, wn = wave & 1;
  const int fr = lane & 15, quad = lane >> 4;
  const int row0 = blockIdx.y * 64, col0 = blockIdx.x * 128, hcol0 = blockIdx.x * 16;

  f32x4 acc[2][4] = {};
  f32x4 lacc = {};

  for (int kt = 0; kt < N_DIM; kt += 64) {
#pragma unroll
    for (int u = 0; u < 2; ++u) {   // A: x tile, 512 chunks
      int s = tid + u * 256, m = s >> 3, cp = s & 7, c = cp ^ (m & 7);
      stage16(xb + (size_t)(row0 + m) * N_DIM + kt + c * 8, As + s * 8);
    }
#pragma unroll
    for (int u = 0; u < 4; ++u) {   // B: betab tile, 1024 chunks
      int s = tid + u * 256, m = s >> 3, cp = s & 7, c = cp ^ (m & 7);
      stage16(betab + (size_t)(col0 + m) * N_DIM + kt + c * 8, Bs + s * 8);
    }
    {                               // W: 16 h rows x (lo64|hi64), 256 chunks
      int m = tid >> 4, cp = tid & 15, c = cp ^ m;
      int col = (c >> 3) * N_DIM + kt + (c & 7) * 8;
      stage16(combW + (size_t)(hcol0 + m) * 1024 + col, Ws + tid * 8);
    }
    __syncthreads();

#pragma unroll
    for (int kk2 = 0; kk2 < 2; ++kk2) {
      const int cbase = kk2 * 4 + quad;
      short8 af[2], bf[4];
#pragma unroll
      for (int i = 0; i < 2; ++i) {
        int m = wm * 32 + i * 16 + fr;
        af[i] = *(const short8*)(As + (m * 8 + (cbase ^ (m & 7))) * 8);
      }
#pragma unroll
      for (int j = 0; j < 4; ++j) {
        int m = wn * 64 + j * 16 + fr;
        bf[j] = *(const short8*)(Bs + (m * 8 + (cbase ^ (m & 7))) * 8);
      }
      short8 wlo = *(const short8*)(Ws + (fr * 16 + (cbase ^ fr)) * 8);
      short8 whi = *(const short8*)(Ws + (fr * 16 + ((8 + cbase) ^ fr)) * 8);
#pragma unroll
      for (int i = 0; i < 2; ++i)
#pragma unroll
        for (int j = 0; j < 4; ++j)
          acc[i][j] = __builtin_amdgcn_mfma_f32_16x16x32_bf16(af[i], bf[j], acc[i][j], 0, 0, 0);
      // linear: wave's 16 rows (af[wn]), both halves into one accumulator
      lacc = __builtin_amdgcn_mfma_f32_16x16x32_bf16(af[wn], wlo, lacc, 0, 0, 0);
      lacc = __builtin_amdgcn_mfma_f32_16x16x32_bf16(sq8(af[wn]), whi, lacc, 0, 0, 0);
    }
    __syncthreads();
  }

  // ---- epilogue: lin rows (disjoint per wave) + FM butterfly meet in LDS ----
  float* red = (float*)As;   // 64 x 20 f32 = 5 KB (As free after last sync)
#pragma unroll
  for (int r = 0; r < 4; ++r)
    red[(wm * 32 + wn * 16 + quad * 4 + r) * 20 + fr] = lacc[r];
  __syncthreads();
  // FM: C/D layout col=lane&15 (hl-local), row=quad*4+reg; butterfly over l
#pragma unroll
  for (int i = 0; i < 2; ++i)
#pragma unroll
    for (int j = 0; j < 4; ++j) {
      const int hin = wn * 8 + j * 2 + (fr >> 3);
#pragma unroll
      for (int r = 0; r < 4; ++r) {
        float v = acc[i][j][r];
        v = v * v;
        v += __shfl_xor(v, 1);
        v += __shfl_xor(v, 2);
        v += __shfl_xor(v, 4);
        if ((lane & 7) == 0)
          red[(wm * 32 + i * 16 + quad * 4 + r) * 20 + hin] += 0.5f * v;
      }
    }
  __syncthreads();
  {
    int r = tid >> 2, hc4 = (tid & 3) * 4;     // 64 rows x 16 h
    f32x4 b4 = *(const f32x4*)(bias + hcol0 + hc4);
    f32x4 v  = *(const f32x4*)(red + r * 20 + hc4);
    f32x4 o;
#pragma unroll
    for (int c = 0; c < 4; ++c) o[c] = v[c] + b4[c];
    *(f32x4*)(out + (size_t)(row0 + r) * H_DIM + hcol0 + hc4) = o;
  }
}

extern "C" void kernel_launch(void* const* d_in, const int* in_sizes, int n_in,
                              void* d_out, int out_size, void* d_ws, size_t ws_size,
                              hipStream_t stream) {
  const float* x    = (const float*)d_in[0];  // (4096, 512)
  const float* beta = (const float*)d_in[1];  // (1024, 8, 512)
  const float* W    = (const float*)d_in[2];  // (1024, 512)
  const float* bias = (const float*)d_in[3];  // (1024,)
  float* out = (float*)d_out;                 // (4096, 1024)

  uint16_t* xb    = (uint16_t*)d_ws;                        // 4096*512 bf16 = 4 MB
  uint16_t* betab = xb + (size_t)B_DIM * N_DIM;             // 8192*512 bf16 = 8 MB
  uint16_t* combW = betab + (size_t)HL * N_DIM;             // 1024*1024 bf16 = 2 MB

  const int prep_threads = PREP_T2 + PREP_T0 + PREP_T1;     // 851968
  prep_kernel<<<prep_threads / 256, 256, 0, stream>>>(x, beta, W, xb, betab, combW);

  // 4096 blocks: 64 b-rows x 128 hl-cols (= 16 h) each, lin fused, 3 blocks/CU
  gemm_kernel<<<dim3(HL / 128, B_DIM / 64), 256, 0, stream>>>(
      xb, betab, combW, bias, out);
}